// Round 2
// baseline (391.845 us; speedup 1.0000x reference)
//
#include <hip/hip_runtime.h>

#define BINS 10

// Quad-per-row (C=16 -> one float4 per lane, 4 lanes/row). A wave's 64 lanes
// cover 16 consecutive rows = 1 KiB contiguous per load instruction (fully
// coalesced, 16x 64B lines/instr — vs 64 lines/instr for row-per-thread).
// Quad reductions via __shfl_xor (DPP, ~free). Histogram accumulates in
// per-thread REGISTERS (statically-indexed unrolled predicated adds -> no
// scratch, no per-row LDS f64 atomics which serialized on the 2 hot bins).
__global__ __launch_bounds__(256) void ghm_main(const float* __restrict__ x,
                                                const int* __restrict__ tgt,
                                                double* __restrict__ g_sum,
                                                unsigned int* __restrict__ g_cnt,
                                                int n_rows) {
    __shared__ double s_sum[BINS];
    __shared__ unsigned int s_cnt[BINS];
    if (threadIdx.x < BINS) { s_sum[threadIdx.x] = 0.0; s_cnt[threadIdx.x] = 0u; }
    __syncthreads();

    // Exact fp32 edges matching jnp.arange(11)/10 (correctly-rounded k/10).
    const float edges[BINS + 1] = {0.0f, 0.1f, 0.2f, 0.3f, 0.4f, 0.5f,
                                   0.6f, 0.7f, 0.8f, 0.9f, 1.0f};

    double acc[BINS];
    unsigned int cnt[BINS];
#pragma unroll
    for (int k = 0; k < BINS; ++k) { acc[k] = 0.0; cnt[k] = 0u; }

    const int j = threadIdx.x & 3;                                   // lane-in-quad
    const int quad = (blockIdx.x * blockDim.x + threadIdx.x) >> 2;   // global row slot
    const int quads_total = (gridDim.x * blockDim.x) >> 2;

    for (int row = quad; row < n_rows; row += quads_total) {
        const float4 v = ((const float4*)x)[row * 4 + j];

        // quad max (fmax exact/order-independent)
        float m = fmaxf(fmaxf(v.x, v.y), fmaxf(v.z, v.w));
        m = fmaxf(m, __shfl_xor(m, 1));
        m = fmaxf(m, __shfl_xor(m, 2));

        // quad sum of exp(x - m); lane0 result = (s0+s1)+(s2+s3), identical
        // rounding order to the previously verified kernels (absmax 0.0).
        float s = expf(v.x - m) + expf(v.y - m) + expf(v.z - m) + expf(v.w - m);
        s += __shfl_xor(s, 1);
        s += __shfl_xor(s, 2);

        if (j == 0) {
            const int t = tgt[row];  // 0 or 1 (classes 0..3 live in this lane's v)
            const float xt = (t == 0) ? v.x : ((t == 1) ? v.y : ((t == 2) ? v.z : v.w));
            const float logp = xt - m - logf(s);   // log_softmax at target
            const float p = expf(logp);            // p_t
            const float g = fabsf(p - (float)t);   // gradient norm

            // searchsorted(edges, g, 'right') - 1, clipped to [0, BINS-1]
            int b = 0;
#pragma unroll
            for (int k = 1; k <= BINS; ++k) b += (g >= edges[k]) ? 1 : 0;
            if (b > BINS - 1) b = BINS - 1;

            // Register histogram: static indices only (unrolled predicated adds).
            const double nll = (double)(-logp);
#pragma unroll
            for (int k = 0; k < BINS; ++k) {
                const bool h = (b == k);
                acc[k] += h ? nll : 0.0;
                cnt[k] += h ? 1u : 0u;
            }
        }
    }

    // Per-thread -> per-block LDS merge, once at the end. Only j==0 lanes have
    // nonzero state, and typically only ~2-4 of their 10 bins are occupied.
#pragma unroll
    for (int k = 0; k < BINS; ++k) {
        if (cnt[k] != 0u) {
            atomicAdd(&s_cnt[k], cnt[k]);
            atomicAdd(&s_sum[k], acc[k]);
        }
    }
    __syncthreads();

    // Block -> global, padded to 128-B stride per bin so different bins land in
    // different L2 lines (2048 blocks hammer these at kernel end).
    if (threadIdx.x < BINS) {
        if (s_cnt[threadIdx.x] != 0u) {
            atomicAdd(&g_cnt[threadIdx.x * 32], s_cnt[threadIdx.x]);
            atomicAdd(&g_sum[threadIdx.x * 16], s_sum[threadIdx.x]);
        }
    }
}

__global__ void ghm_final(const double* __restrict__ g_sum,
                          const unsigned int* __restrict__ g_cnt,
                          float* __restrict__ out, int n_rows) {
    if (threadIdx.x == 0 && blockIdx.x == 0) {
        const double scale = (double)n_rows / (double)BINS;
        double total = 0.0;
        for (int b = 0; b < BINS; ++b) {
            double c = (double)g_cnt[b * 32];
            if (c < 1.0) c = 1.0;
            total += g_sum[b * 16] / c;
        }
        out[0] = (float)(total * scale);
    }
}

extern "C" void kernel_launch(void* const* d_in, const int* in_sizes, int n_in,
                              void* d_out, int out_size, void* d_ws, size_t ws_size,
                              hipStream_t stream) {
    const float* x = (const float*)d_in[0];
    const int* tgt = (const int*)d_in[1];
    const int n_rows = in_sizes[1];  // N = 4194304 (inputs are N x 16)

    // Padded layout: g_sum = 10 bins * 16 doubles (128 B stride) at d_ws,
    //                g_cnt = 10 bins * 32 uints   (128 B stride) at d_ws+2048.
    double* g_sum = (double*)d_ws;
    unsigned int* g_cnt = (unsigned int*)((char*)d_ws + 2048);

    // d_ws is re-poisoned to 0xAA before every timed launch — zero the histogram.
    hipMemsetAsync(d_ws, 0, 4096, stream);

    const int block = 256;
    const int grid = 2048;  // 131072 quads -> 32 rows/quad grid-stride
    ghm_main<<<grid, block, 0, stream>>>(x, tgt, g_sum, g_cnt, n_rows);
    ghm_final<<<1, 64, 0, stream>>>(g_sum, g_cnt, (float*)d_out, n_rows);
}